// Round 2
// baseline (409.141 us; speedup 1.0000x reference)
//
#include <hip/hip_runtime.h>

// RRSVM: per (b,c,h,w) take 3x3 zero-padded window, stable-argsort descending,
// out = sum_r v_sorted[r]*s[c,r]; indices emitted as float-encoded ints.
//
// R10: DIAGNOSTIC ROUND (intentionally ~3*T_kernel slower). The top-5
// rocprof table is monopolized by ~158us harness poison-fills, so the rrsvm
// dispatch's counters are invisible and two incompatible stories fit dur_us:
//   Story 1: kernel ~111us (2.5x over its 45us HBM-write floor) -> headroom.
//   Story 2: kernel ~50us (at roofline); rest is fill + tiny restore dispatches.
// Fix: repeat the ENTIRE body REPS=4 times (bit-identical idempotent stores,
// wave-local LDS rewritten with same values -> race-free, output unchanged).
// This (a) pushes the kernel dispatch to 4*T_k > 160us so it tops the counter
// table (revealing VGPR_Count / Occupancy / VALUBusy / WRITE_SIZE / hbm_gbps),
// and (b) makes dur_us = base + 3*T_k, measuring T_k exactly.
// Next round reverts REPS and acts on the revealed counters.

#define B_ 16
#define C_ 128
#define H_ 56
#define W_ 56
#define HW (H_*W_)           // 3136
#define NPIX (B_*C_*H_*W_)   // 6422528
#define BLK 256
#define PXT 4
#define PXB (BLK * PXT)      // 1024 pixels per block region
#define GRID (NPIX / PXB)    // 6272
#define REPS 4               // diagnostic repeat; revert to 1 after readout

typedef float v4f __attribute__((ext_vector_type(4)));

__global__ __launch_bounds__(BLK) void rrsvm_kernel(
    const float* __restrict__ x, const float* __restrict__ s,
    float* __restrict__ out, float* __restrict__ idxout)
{
    __shared__ unsigned char lds_idx[PXB * 9];   // 9216 B, byte-staged indices
    __shared__ float lds_s[24];                  // <=2 channels x 9 weights

    #pragma unroll 1
    for (int rep = 0; rep < REPS; ++rep) {

    const int tid  = threadIdx.x;
    const int lane = tid & 63;
    const int wv   = tid >> 6;
    const int pixr = blockIdx.x * PXB;
    const int pix0 = pixr + tid * PXT;   // contiguous quad, 16B-aligned
    const int w0   = pix0 % W_;          // in {0,4,...,52} (quad shares a row)
    const int t    = pix0 / W_;
    const int h    = t % H_;
    const int bc   = t / H_;

    // ---- per-WAVE staging of s (duplicate same-value writes, no barrier) ----
    const int bcf = pixr / HW;
    const int bcl = (pixr + PXB - 1) / HW;
    if (lane < 18) {
        const int which = (lane >= 9);
        const int bcx   = which ? bcl : bcf;
        lds_s[lane] = s[(bcx & (C_ - 1)) * 9 + lane - which * 9];
    }
    const int sbase = (bc == bcf) ? 0 : 9;

    // ---- gather 3 rows x 6 cols: float4 middle + 2 clamped edge scalars ----
    const float* img = x + (size_t)bc * HW;
    const int r0 = (h > 0)      ? h - 1 : 0;
    const int r2 = (h < H_ - 1) ? h + 1 : H_ - 1;
    const int cl = (w0 > 0)        ? w0 - 1 : 0;
    const int cr = (w0 < W_ - PXT) ? w0 + 4 : W_ - 1;
    const float* p0 = img + r0 * W_;
    const float* p1 = img + h  * W_;
    const float* p2 = img + r2 * W_;

    float T[3][6];
    {
        v4f m0 = *(const v4f*)(p0 + w0);
        v4f m1 = *(const v4f*)(p1 + w0);
        v4f m2 = *(const v4f*)(p2 + w0);
        T[0][0] = p0[cl]; T[0][1] = m0.x; T[0][2] = m0.y; T[0][3] = m0.z; T[0][4] = m0.w; T[0][5] = p0[cr];
        T[1][0] = p1[cl]; T[1][1] = m1.x; T[1][2] = m1.y; T[1][3] = m1.z; T[1][4] = m1.w; T[1][5] = p1[cr];
        T[2][0] = p2[cl]; T[2][1] = m2.x; T[2][2] = m2.y; T[2][3] = m2.z; T[2][4] = m2.w; T[2][5] = p2[cr];
    }
    const bool rv0 = (h > 0), rv2 = (h < H_ - 1);
    const bool cvL = (w0 > 0), cvR = (w0 < W_ - PXT);
    #pragma unroll
    for (int j = 0; j < 6; ++j) {
        T[0][j] = rv0 ? T[0][j] : 0.0f;
        T[2][j] = rv2 ? T[2][j] : 0.0f;
    }
    T[0][0] = cvL ? T[0][0] : 0.0f;
    T[1][0] = cvL ? T[1][0] : 0.0f;
    T[2][0] = cvL ? T[2][0] : 0.0f;
    T[0][5] = cvR ? T[0][5] : 0.0f;
    T[1][5] = cvR ? T[1][5] : 0.0f;
    T[2][5] = cvR ? T[2][5] : 0.0f;

    // NOTE: no __syncthreads -- lds_s was written by this wave's own lanes;
    // in-order per-wave DS + compiler may-alias dependence order the reads.

    float oacc[PXT];
    #pragma unroll
    for (int px = 0; px < PXT; ++px) {
        const float v[9] = { T[0][px], T[0][px+1], T[0][px+2],
                             T[1][px], T[1][px+1], T[1][px+2],
                             T[2][px], T[2][px+1], T[2][px+2] };
        // rank_k = #elements placed before k in stable descending order
        int rank[9];
        #pragma unroll
        for (int k = 0; k < 9; ++k) rank[k] = 8 - k;
        #pragma unroll
        for (int a = 0; a < 8; ++a)
            #pragma unroll
            for (int b = a + 1; b < 9; ++b) {
                const int g = (v[a] >= v[b]);   // CSE'd across adjacent windows
                rank[b] += g;
                rank[a] -= g;
            }
        // scatter idx byte (argsort inversion) + weighted sum via s[rank]
        const int base_b = tid * 36 + px * 9;
        float acc = 0.0f;
        #pragma unroll
        for (int k = 0; k < 9; ++k) {
            lds_idx[base_b + rank[k]] = (unsigned char)k;
            acc = fmaf(v[k], lds_s[sbase + rank[k]], acc);
        }
        oacc[px] = acc;
    }
    v4f o; o.x = oacc[0]; o.y = oacc[1]; o.z = oacc[2]; o.w = oacc[3];
    __builtin_nontemporal_store(o, (v4f*)(out + pix0));

    // compiler fence: keep the slab readback after the byte scatter
    // (hardware orders same-wave DS ops; this pins the compiler too)
    asm volatile("" ::: "memory");

    // ---- wave-local writeback: dword (576w + lane + 64k) = 4 idx bytes ----
    // Each wave reads/writes only its own 2304B slab -> no cross-wave dep.
    const unsigned int* lu = (const unsigned int*)lds_idx;
    v4f* dst = (v4f*)(idxout + (size_t)pixr * 9);
    const int base = wv * 576 + lane;
    #pragma unroll
    for (int k = 0; k < 9; ++k) {
        const unsigned int u = lu[base + 64 * k];
        v4f f;
        f.x = (float)( u        & 0xff);
        f.y = (float)((u >>  8) & 0xff);
        f.z = (float)((u >> 16) & 0xff);
        f.w = (float)((u >> 24)       );
        __builtin_nontemporal_store(f, dst + base + 64 * k);
    }

    asm volatile("" ::: "memory");   // keep reps ordered, no cross-rep merge
    } // rep
}

extern "C" void kernel_launch(void* const* d_in, const int* in_sizes, int n_in,
                              void* d_out, int out_size, void* d_ws, size_t ws_size,
                              hipStream_t stream) {
    const float* x = (const float*)d_in[0];   // [16,128,56,56]
    const float* s = (const float*)d_in[1];   // [128,3,3]
    float* out    = (float*)d_out;            // first NPIX floats
    float* idxout = out + NPIX;               // then NPIX*9 float-encoded ints

    rrsvm_kernel<<<GRID, BLK, 0, stream>>>(x, s, out, idxout);
}

// Round 3
// 276.735 us; speedup vs baseline: 1.4785x; 1.4785x over previous
//
#include <hip/hip_runtime.h>

// RRSVM: per (b,c,h,w) take 3x3 zero-padded window, stable-argsort descending,
// out = sum_r v_sorted[r]*s[c,r]; indices emitted as float-encoded ints.
//
// R11: R9 (barrier-free, wave-local transpose) with NT store hints REMOVED.
// R10 diagnostic (REPS=4) established: rest-of-graph ~194us (fill 160 + tiny
// dispatches), kernel standalone ~77us vs a ~44us write floor; during the
// kernel hbm=4.78 TB/s (75% of fill's 6.4 on the same buffer), VALU 17%,
// occupancy 36% -> latency/store-path bound, nothing saturated.
// Theory: __builtin_nontemporal_store bypasses L2 write-combining; finite
// NT queue depth throttles at ~11 waves/CU, and rep-1 NT stores collide with
// the poison-fill's dirty L2/L3 lines (77us first rep vs 46us marginal).
// Plain stores write-hit those dirty lines in L2 and let L2 smooth writeback
// -> predicted kernel 77->~62us, dur_us 271 -> ~256.
// Store lane-contiguity (the actual R4 lesson) is preserved exactly.

#define B_ 16
#define C_ 128
#define H_ 56
#define W_ 56
#define HW (H_*W_)           // 3136
#define NPIX (B_*C_*H_*W_)   // 6422528
#define BLK 256
#define PXT 4
#define PXB (BLK * PXT)      // 1024 pixels per block region
#define GRID (NPIX / PXB)    // 6272

typedef float v4f __attribute__((ext_vector_type(4)));

__global__ __launch_bounds__(BLK) void rrsvm_kernel(
    const float* __restrict__ x, const float* __restrict__ s,
    float* __restrict__ out, float* __restrict__ idxout)
{
    __shared__ unsigned char lds_idx[PXB * 9];   // 9216 B, byte-staged indices
    __shared__ float lds_s[24];                  // <=2 channels x 9 weights

    const int tid  = threadIdx.x;
    const int lane = tid & 63;
    const int wv   = tid >> 6;
    const int pixr = blockIdx.x * PXB;
    const int pix0 = pixr + tid * PXT;   // contiguous quad, 16B-aligned
    const int w0   = pix0 % W_;          // in {0,4,...,52} (quad shares a row)
    const int t    = pix0 / W_;
    const int h    = t % H_;
    const int bc   = t / H_;

    // ---- per-WAVE staging of s (duplicate same-value writes, no barrier) ----
    const int bcf = pixr / HW;
    const int bcl = (pixr + PXB - 1) / HW;
    if (lane < 18) {
        const int which = (lane >= 9);
        const int bcx   = which ? bcl : bcf;
        lds_s[lane] = s[(bcx & (C_ - 1)) * 9 + lane - which * 9];
    }
    const int sbase = (bc == bcf) ? 0 : 9;

    // ---- gather 3 rows x 6 cols: float4 middle + 2 clamped edge scalars ----
    const float* img = x + (size_t)bc * HW;
    const int r0 = (h > 0)      ? h - 1 : 0;
    const int r2 = (h < H_ - 1) ? h + 1 : H_ - 1;
    const int cl = (w0 > 0)        ? w0 - 1 : 0;
    const int cr = (w0 < W_ - PXT) ? w0 + 4 : W_ - 1;
    const float* p0 = img + r0 * W_;
    const float* p1 = img + h  * W_;
    const float* p2 = img + r2 * W_;

    float T[3][6];
    {
        v4f m0 = *(const v4f*)(p0 + w0);
        v4f m1 = *(const v4f*)(p1 + w0);
        v4f m2 = *(const v4f*)(p2 + w0);
        T[0][0] = p0[cl]; T[0][1] = m0.x; T[0][2] = m0.y; T[0][3] = m0.z; T[0][4] = m0.w; T[0][5] = p0[cr];
        T[1][0] = p1[cl]; T[1][1] = m1.x; T[1][2] = m1.y; T[1][3] = m1.z; T[1][4] = m1.w; T[1][5] = p1[cr];
        T[2][0] = p2[cl]; T[2][1] = m2.x; T[2][2] = m2.y; T[2][3] = m2.z; T[2][4] = m2.w; T[2][5] = p2[cr];
    }
    const bool rv0 = (h > 0), rv2 = (h < H_ - 1);
    const bool cvL = (w0 > 0), cvR = (w0 < W_ - PXT);
    #pragma unroll
    for (int j = 0; j < 6; ++j) {
        T[0][j] = rv0 ? T[0][j] : 0.0f;
        T[2][j] = rv2 ? T[2][j] : 0.0f;
    }
    T[0][0] = cvL ? T[0][0] : 0.0f;
    T[1][0] = cvL ? T[1][0] : 0.0f;
    T[2][0] = cvL ? T[2][0] : 0.0f;
    T[0][5] = cvR ? T[0][5] : 0.0f;
    T[1][5] = cvR ? T[1][5] : 0.0f;
    T[2][5] = cvR ? T[2][5] : 0.0f;

    // NOTE: no __syncthreads -- lds_s was written by this wave's own lanes;
    // in-order per-wave DS + compiler may-alias dependence order the reads.

    float oacc[PXT];
    #pragma unroll
    for (int px = 0; px < PXT; ++px) {
        const float v[9] = { T[0][px], T[0][px+1], T[0][px+2],
                             T[1][px], T[1][px+1], T[1][px+2],
                             T[2][px], T[2][px+1], T[2][px+2] };
        // rank_k = #elements placed before k in stable descending order
        int rank[9];
        #pragma unroll
        for (int k = 0; k < 9; ++k) rank[k] = 8 - k;
        #pragma unroll
        for (int a = 0; a < 8; ++a)
            #pragma unroll
            for (int b = a + 1; b < 9; ++b) {
                const int g = (v[a] >= v[b]);   // CSE'd across adjacent windows
                rank[b] += g;
                rank[a] -= g;
            }
        // scatter idx byte (argsort inversion) + weighted sum via s[rank]
        const int base_b = tid * 36 + px * 9;
        float acc = 0.0f;
        #pragma unroll
        for (int k = 0; k < 9; ++k) {
            lds_idx[base_b + rank[k]] = (unsigned char)k;
            acc = fmaf(v[k], lds_s[sbase + rank[k]], acc);
        }
        oacc[px] = acc;
    }
    v4f o; o.x = oacc[0]; o.y = oacc[1]; o.z = oacc[2]; o.w = oacc[3];
    *(v4f*)(out + pix0) = o;   // plain store: L2 write path (R11 change)

    // compiler fence: keep the slab readback after the byte scatter
    // (hardware orders same-wave DS ops; this pins the compiler too)
    asm volatile("" ::: "memory");

    // ---- wave-local writeback: dword (576w + lane + 64k) = 4 idx bytes ----
    // Each wave reads/writes only its own 2304B slab -> no cross-wave dep.
    const unsigned int* lu = (const unsigned int*)lds_idx;
    v4f* dst = (v4f*)(idxout + (size_t)pixr * 9);
    const int base = wv * 576 + lane;
    #pragma unroll
    for (int k = 0; k < 9; ++k) {
        const unsigned int u = lu[base + 64 * k];
        v4f f;
        f.x = (float)( u        & 0xff);
        f.y = (float)((u >>  8) & 0xff);
        f.z = (float)((u >> 16) & 0xff);
        f.w = (float)((u >> 24)       );
        dst[base + 64 * k] = f;   // plain store (R11 change)
    }
}

extern "C" void kernel_launch(void* const* d_in, const int* in_sizes, int n_in,
                              void* d_out, int out_size, void* d_ws, size_t ws_size,
                              hipStream_t stream) {
    const float* x = (const float*)d_in[0];   // [16,128,56,56]
    const float* s = (const float*)d_in[1];   // [128,3,3]
    float* out    = (float*)d_out;            // first NPIX floats
    float* idxout = out + NPIX;               // then NPIX*9 float-encoded ints

    rrsvm_kernel<<<GRID, BLK, 0, stream>>>(x, s, out, idxout);
}

// Round 4
// 273.189 us; speedup vs baseline: 1.4976x; 1.0130x over previous
//
#include <hip/hip_runtime.h>

// RRSVM: per (b,c,h,w) take 3x3 zero-padded window, stable-argsort descending,
// out = sum_r v_sorted[r]*s[c,r]; indices emitted as float-encoded ints.
//
// R12: persistent grid-stride blocks. Evidence chain:
//  - R10 (REPS=4): marginal rep 46us ~= 44us write floor -> steady-state
//    engine is AT roofline when waves stay resident; standalone kernel 77us.
//  - Occupancy 36% despite limits allowing 100% (VGPR=64, LDS 9.7KB);
//    VALU 17%, LDS ~30%, HBM 59% -> nothing saturated: launch/ramp-bound
//    (6272 short blocks drain & relaunch).
//  - R11: plain stores regressed (276.7 vs 271.3) -> NT stores restored.
// Fix: GRID=2048 (8 blocks/CU x 256 CU co-resident), each block grid-strides
// over 3-4 regions -> waves stay resident like the REPS loop did.
// lds_s made per-wave [4][24]: free-running waves on different iterations
// must not share weight slots (only cross-wave LDS dep removed).
// Everything else identical to R9 (barrier-free wave-local idx transpose,
// NT 1KB lane-contiguous stores, R7 rank core).

#define B_ 16
#define C_ 128
#define H_ 56
#define W_ 56
#define HW (H_*W_)           // 3136
#define NPIX (B_*C_*H_*W_)   // 6422528
#define BLK 256
#define PXT 4
#define PXB (BLK * PXT)      // 1024 pixels per block region
#define NREG (NPIX / PXB)    // 6272 regions
#define NBLK 2048            // 8 blocks/CU x 256 CU, co-resident

typedef float v4f __attribute__((ext_vector_type(4)));

__global__ __launch_bounds__(BLK) void rrsvm_kernel(
    const float* __restrict__ x, const float* __restrict__ s,
    float* __restrict__ out, float* __restrict__ idxout)
{
    __shared__ unsigned char lds_idx[PXB * 9];   // 9216 B, byte-staged indices
    __shared__ float lds_s[4][24];               // per-wave weight slots

    const int tid  = threadIdx.x;
    const int lane = tid & 63;
    const int wv   = tid >> 6;

    #pragma unroll 1
    for (int reg = blockIdx.x; reg < NREG; reg += NBLK) {

    const int pixr = reg * PXB;
    const int pix0 = pixr + tid * PXT;   // contiguous quad, 16B-aligned
    const int w0   = pix0 % W_;          // in {0,4,...,52} (quad shares a row)
    const int t    = pix0 / W_;
    const int h    = t % H_;
    const int bc   = t / H_;

    // ---- per-WAVE staging of s (wave-private slot, no barrier, no race) ----
    const int bcf = pixr / HW;
    const int bcl = (pixr + PXB - 1) / HW;
    if (lane < 18) {
        const int which = (lane >= 9);
        const int bcx   = which ? bcl : bcf;
        lds_s[wv][lane] = s[(bcx & (C_ - 1)) * 9 + lane - which * 9];
    }
    const int sbase = (bc == bcf) ? 0 : 9;

    // ---- gather 3 rows x 6 cols: float4 middle + 2 clamped edge scalars ----
    const float* img = x + (size_t)bc * HW;
    const int r0 = (h > 0)      ? h - 1 : 0;
    const int r2 = (h < H_ - 1) ? h + 1 : H_ - 1;
    const int cl = (w0 > 0)        ? w0 - 1 : 0;
    const int cr = (w0 < W_ - PXT) ? w0 + 4 : W_ - 1;
    const float* p0 = img + r0 * W_;
    const float* p1 = img + h  * W_;
    const float* p2 = img + r2 * W_;

    float T[3][6];
    {
        v4f m0 = *(const v4f*)(p0 + w0);
        v4f m1 = *(const v4f*)(p1 + w0);
        v4f m2 = *(const v4f*)(p2 + w0);
        T[0][0] = p0[cl]; T[0][1] = m0.x; T[0][2] = m0.y; T[0][3] = m0.z; T[0][4] = m0.w; T[0][5] = p0[cr];
        T[1][0] = p1[cl]; T[1][1] = m1.x; T[1][2] = m1.y; T[1][3] = m1.z; T[1][4] = m1.w; T[1][5] = p1[cr];
        T[2][0] = p2[cl]; T[2][1] = m2.x; T[2][2] = m2.y; T[2][3] = m2.z; T[2][4] = m2.w; T[2][5] = p2[cr];
    }
    const bool rv0 = (h > 0), rv2 = (h < H_ - 1);
    const bool cvL = (w0 > 0), cvR = (w0 < W_ - PXT);
    #pragma unroll
    for (int j = 0; j < 6; ++j) {
        T[0][j] = rv0 ? T[0][j] : 0.0f;
        T[2][j] = rv2 ? T[2][j] : 0.0f;
    }
    T[0][0] = cvL ? T[0][0] : 0.0f;
    T[1][0] = cvL ? T[1][0] : 0.0f;
    T[2][0] = cvL ? T[2][0] : 0.0f;
    T[0][5] = cvR ? T[0][5] : 0.0f;
    T[1][5] = cvR ? T[1][5] : 0.0f;
    T[2][5] = cvR ? T[2][5] : 0.0f;

    // NOTE: no __syncthreads -- all LDS deps are within this wave;
    // in-order per-wave DS + compiler may-alias dependence order them.

    float oacc[PXT];
    #pragma unroll
    for (int px = 0; px < PXT; ++px) {
        const float v[9] = { T[0][px], T[0][px+1], T[0][px+2],
                             T[1][px], T[1][px+1], T[1][px+2],
                             T[2][px], T[2][px+1], T[2][px+2] };
        // rank_k = #elements placed before k in stable descending order
        int rank[9];
        #pragma unroll
        for (int k = 0; k < 9; ++k) rank[k] = 8 - k;
        #pragma unroll
        for (int a = 0; a < 8; ++a)
            #pragma unroll
            for (int b = a + 1; b < 9; ++b) {
                const int g = (v[a] >= v[b]);   // CSE'd across adjacent windows
                rank[b] += g;
                rank[a] -= g;
            }
        // scatter idx byte (argsort inversion) + weighted sum via s[rank]
        const int base_b = tid * 36 + px * 9;
        float acc = 0.0f;
        #pragma unroll
        for (int k = 0; k < 9; ++k) {
            lds_idx[base_b + rank[k]] = (unsigned char)k;
            acc = fmaf(v[k], lds_s[wv][sbase + rank[k]], acc);
        }
        oacc[px] = acc;
    }
    v4f o; o.x = oacc[0]; o.y = oacc[1]; o.z = oacc[2]; o.w = oacc[3];
    __builtin_nontemporal_store(o, (v4f*)(out + pix0));

    // compiler fence: keep the slab readback after the byte scatter
    // (hardware orders same-wave DS ops; this pins the compiler too)
    asm volatile("" ::: "memory");

    // ---- wave-local writeback: dword (576w + lane + 64k) = 4 idx bytes ----
    // Each wave reads/writes only its own 2304B slab -> no cross-wave dep.
    const unsigned int* lu = (const unsigned int*)lds_idx;
    v4f* dst = (v4f*)(idxout + (size_t)pixr * 9);
    const int base = wv * 576 + lane;
    #pragma unroll
    for (int k = 0; k < 9; ++k) {
        const unsigned int u = lu[base + 64 * k];
        v4f f;
        f.x = (float)( u        & 0xff);
        f.y = (float)((u >>  8) & 0xff);
        f.z = (float)((u >> 16) & 0xff);
        f.w = (float)((u >> 24)       );
        __builtin_nontemporal_store(f, dst + base + 64 * k);
    }

    asm volatile("" ::: "memory");   // next iteration overwrites the slab
    } // reg
}

extern "C" void kernel_launch(void* const* d_in, const int* in_sizes, int n_in,
                              void* d_out, int out_size, void* d_ws, size_t ws_size,
                              hipStream_t stream) {
    const float* x = (const float*)d_in[0];   // [16,128,56,56]
    const float* s = (const float*)d_in[1];   // [128,3,3]
    float* out    = (float*)d_out;            // first NPIX floats
    float* idxout = out + NPIX;               // then NPIX*9 float-encoded ints

    rrsvm_kernel<<<NBLK, BLK, 0, stream>>>(x, s, out, idxout);
}